// Round 4
// baseline (181.939 us; speedup 1.0000x reference)
//
#include <hip/hip_runtime.h>
#include <hip/hip_bf16.h>
#include <hip/hip_fp8.h>

// SNN forward, round 4.
//   prep:      w1 -> w1frag bf16 fragment layout (as R3)
//   gemm_mfma: BM=64 x BN=256, 256 thr / 4 waves, wave tile 64x64 (acc=64
//              VGPR -> 4 waves/SIMD, ~4 blocks/CU). A reg-staged f32->bf16
//              into LDS (stride 80, dbuf), B streamed L2->reg per k-tile.
//              Raw s_barrier + manual lgkmcnt keeps A-stage loads in flight
//              across barriers (counted-vmcnt discipline). iff stored fp8.
//   snn_recur: 1 wave per batch row; fp8 iff; single-ballot fast path.

#define B_    256
#define T_    250
#define NIN   700
#define KPAD  704
#define NKT   22          // KPAD/32
#define NHID  512
#define NOUT  20

typedef __attribute__((ext_vector_type(8))) short short8;
typedef __attribute__((ext_vector_type(4))) float f32x4;

static __device__ __forceinline__ ushort f2bf(float f) {
  union { float f; unsigned u; } v; v.f = f;
  unsigned r = (v.u + 0x7FFF + ((v.u >> 16) & 1)) >> 16;  // RNE
  return (ushort)r;
}
static __device__ __forceinline__ unsigned cvtpk_bf16(float a, float b) {
  unsigned r;
  asm("v_cvt_pk_bf16_f32 %0, %1, %2" : "=v"(r) : "v"(a), "v"(b));
  return r;
}

// ---------------- prep: w1 -> bf16 fragment layout (same as R3) ----------------
// flat = ((kt*32 + colblk)*64 + (koct*16 + colm))*8 + e
__global__ __launch_bounds__(256) void prep_kernel(
    const float* __restrict__ w1, ushort* __restrict__ w1frag) {
  int i = blockIdx.x * 256 + threadIdx.x;
  if (i >= NKT * 32 * 64 * 8) return;
  int e      = i & 7;
  int colm   = (i >> 3) & 15;
  int koct   = (i >> 7) & 3;
  int colblk = (i >> 9) & 31;
  int kt     = i >> 14;
  int k   = kt * 32 + koct * 8 + e;
  int col = colblk * 16 + colm;
  w1frag[i] = (k < NIN) ? f2bf(w1[(size_t)col * NIN + k]) : (ushort)0;
}

// ---------------- MFMA GEMM ----------------
// grid = (2, mchunks); block = 256 (4 waves), wave tile 64 x 64
__global__ __launch_bounds__(256, 4) void gemm_mfma(
    const float* __restrict__ x, const ushort* __restrict__ w1frag,
    unsigned char* __restrict__ iff, int t0) {
  __shared__ __align__(16) char Abuf[2][64 * 80];  // 5KB each, stride-80 rows

  int tid  = threadIdx.x;
  int lane = tid & 63;
  int wave = tid >> 6;           // 0..3 = n-quarter within this n-half
  int n0   = blockIdx.x;         // 0..1 n-half
  int gy   = blockIdx.y;         // m-chunk (64 rows)
  int m0 = gy * 64;
  int t  = t0 + (gy >> 2);
  int b0 = (gy & 3) * 64;

  // A staging: thread -> (row, k-quad)
  int srow = tid >> 2;           // 0..63
  int skq  = tid & 3;            // 8 f32 at k = kt*32 + skq*8
  const float* ap = x + ((size_t)(b0 + srow) * T_ + t) * NIN;
  int swb = srow * 80 + skq * 16;

  int lm = lane & 15, lk = lane >> 4;
  int cb0 = n0 * 16 + wave * 4;  // colblk base for this wave
  const ushort* bbase = w1frag + ((size_t)cb0 * 64 + lane) * 8;

  f32x4 acc[4][4];
#pragma unroll
  for (int i = 0; i < 4; ++i)
#pragma unroll
    for (int j = 0; j < 4; ++j) acc[i][j] = (f32x4){0.f, 0.f, 0.f, 0.f};

#define LOADA(d0, d1, KT) do {                                               \
    int k0_ = (KT) * 32 + skq * 8;                                           \
    if (k0_ + 8 <= NIN) {                                                    \
      d0 = *(const float4*)(ap + k0_); d1 = *(const float4*)(ap + k0_ + 4);  \
    } else if (k0_ + 4 <= NIN) {                                             \
      d0 = *(const float4*)(ap + k0_); d1 = (float4){0.f,0.f,0.f,0.f};       \
    } else { d0 = (float4){0.f,0.f,0.f,0.f}; d1 = (float4){0.f,0.f,0.f,0.f}; } \
  } while (0)

#define WRITEA(BUF, s0, s1) do {                                             \
    uint4 pk_;                                                               \
    pk_.x = cvtpk_bf16(s0.x, s0.y); pk_.y = cvtpk_bf16(s0.z, s0.w);          \
    pk_.z = cvtpk_bf16(s1.x, s1.y); pk_.w = cvtpk_bf16(s1.z, s1.w);          \
    *(uint4*)(&Abuf[BUF][swb]) = pk_;                                        \
  } while (0)

  float4 a0a, a1a, a0b, a1b;   // two A-stage slots

  // prologue: tile0 -> slot a -> Abuf[0]; tile1 -> slot b
  LOADA(a0a, a1a, 0);
  LOADA(a0b, a1b, 1);
  WRITEA(0, a0a, a1a);
  asm volatile("s_waitcnt lgkmcnt(0)" ::: "memory");
  __builtin_amdgcn_s_barrier();
  __builtin_amdgcn_sched_barrier(0);

#pragma unroll 2
  for (int kt = 0; kt < NKT; ++kt) {
    const int cur = kt & 1;
    // B frags for THIS tile (issued first so their vmcnt wait leaves A in flight)
    short8 bf[4];
    {
      const ushort* bp = bbase + (size_t)kt * 16384;
#pragma unroll
      for (int j = 0; j < 4; ++j) bf[j] = *(const short8*)(bp + j * 512);
    }
    // A stage for tile kt+2 into the slot just freed
    if (kt + 2 < NKT) {
      if (cur == 0) { LOADA(a0a, a1a, kt + 2); } else { LOADA(a0b, a1b, kt + 2); }
    }
    // A frags from LDS (shared by all 4 waves)
    short8 af[4];
#pragma unroll
    for (int i = 0; i < 4; ++i)
      af[i] = *(const short8*)(&Abuf[cur][(i * 16 + lm) * 80 + lk * 16]);
    // MFMA cluster
    __builtin_amdgcn_s_setprio(1);
#pragma unroll
    for (int i = 0; i < 4; ++i)
#pragma unroll
      for (int j = 0; j < 4; ++j)
        acc[i][j] = __builtin_amdgcn_mfma_f32_16x16x32_bf16(
            af[i], bf[j], acc[i][j], 0, 0, 0);
    __builtin_amdgcn_s_setprio(0);
    // write tile kt+1 (staged last iteration) into the other buffer
    if (kt + 1 < NKT) {
      if (cur == 0) { WRITEA(1, a0b, a1b); } else { WRITEA(0, a0a, a1a); }
      asm volatile("s_waitcnt lgkmcnt(0)" ::: "memory");
      __builtin_amdgcn_s_barrier();
      __builtin_amdgcn_sched_barrier(0);
    }
  }
#undef LOADA
#undef WRITEA

  // epilogue: C/D layout col=lane&15, row=(lane>>4)*4+reg; store fp8 e4m3
#pragma unroll
  for (int i = 0; i < 4; ++i) {
#pragma unroll
    for (int r = 0; r < 4; ++r) {
      int row = m0 + i * 16 + lk * 4 + r;
      unsigned char* op = iff + (size_t)row * NHID + n0 * 256 + wave * 64 + lm;
#pragma unroll
      for (int j = 0; j < 4; ++j) {
        __hip_fp8_e4m3 q(acc[i][j][r]);
        op[j * 16] = q.__x;
      }
    }
  }
}

// ---------------- fused recurrence ----------------
// 256 blocks x 64 threads; block b = batch row. Lane owns 8 h. fp8 iff.
__global__ __launch_bounds__(64) void snn_recur(
    const unsigned char* __restrict__ iff, const float* __restrict__ wrec,
    const float* __restrict__ wout,
    const float* __restrict__ alpha, const float* __restrict__ rho,
    const float* __restrict__ beta_a, const float* __restrict__ beta_out,
    float* __restrict__ state, float* __restrict__ dout,
    int Tc, int first, int last) {
  int lane = threadIdx.x;
  int b = blockIdx.x;
  int hbase = lane * 8;

  float* v1s = state;
  float* a1s = state + B_ * NHID;
  float* sps = state + 2 * B_ * NHID;
  float* vos = state + 3 * B_ * NHID;
  float* oss = vos + B_ * NOUT;

  float v1[8], a1[8], sp[8], al[8], rh[8], ba[8];
#pragma unroll
  for (int r = 0; r < 8; ++r) {
    int h = hbase + r;
    al[r] = alpha[h]; rh[r] = rho[h]; ba[r] = beta_a[h];
    if (first) { v1[r] = 0.f; a1[r] = 0.f; sp[r] = 0.f; }
    else {
      v1[r] = v1s[(size_t)b * NHID + h];
      a1[r] = a1s[(size_t)b * NHID + h];
      sp[r] = sps[(size_t)b * NHID + h];
    }
  }
  float vout = 0.f, osum = 0.f, bo = 0.f;
  if (lane < NOUT) {
    bo = beta_out[lane];
    if (!first) { vout = vos[b * NOUT + lane]; osum = oss[b * NOUT + lane]; }
  }

  unsigned long long mask[8];
  bool anyprev;
  {
    float ss = sp[0] + sp[1] + sp[2] + sp[3] + sp[4] + sp[5] + sp[6] + sp[7];
    unsigned long long anyb = __ballot(ss != 0.f);
    anyprev = (anyb != 0ull);
#pragma unroll
    for (int r = 0; r < 8; ++r) mask[r] = anyprev ? __ballot(sp[r] != 0.f) : 0ull;
  }

  // depth-8 prefetch ring of 8-byte fp8 rows (static indices, rule #20)
  uint2 pf[8];
#pragma unroll
  for (int j = 0; j < 8; ++j) {
    int tl = (j < Tc) ? j : (Tc - 1);
    pf[j] = *(const uint2*)(iff + ((size_t)tl * B_ + b) * NHID + hbase);
  }

  for (int tb = 0; tb < Tc; tb += 8) {
#pragma unroll
    for (int j = 0; j < 8; ++j) {
      int tl = tb + j;
      if (tl < Tc) {
        float iv[8];
#pragma unroll
        for (int r = 0; r < 8; ++r) {
          unsigned w = (r < 4) ? pf[j].x : pf[j].y;
          __hip_fp8_e4m3 q; q.__x = (unsigned char)((w >> ((r & 3) * 8)) & 255u);
          iv[r] = (float)q;
        }

        if (anyprev) {  // sparse recurrent gather (cold path)
#pragma unroll
          for (int r2 = 0; r2 < 8; ++r2) {
            unsigned long long mm = mask[r2];
            while (mm) {
              int l2 = __ffsll(mm) - 1; mm &= (mm - 1);
              int hp = l2 * 8 + r2;
#pragma unroll
              for (int r = 0; r < 8; ++r)
                iv[r] += wrec[(size_t)(hbase + r) * NHID + hp];
            }
          }
        }

        float s[8];
#pragma unroll
        for (int r = 0; r < 8; ++r) {
          a1[r] = rh[r] * a1[r] + ba[r] * sp[r];
          v1[r] = al[r] * v1[r] + (1.0f - al[r]) * iv[r] - a1[r];
          s[r] = (v1[r] - 1.0f > 0.0f) ? 1.0f : 0.0f;
          v1[r] -= s[r];
          sp[r] = s[r];
        }
        float ss = s[0] + s[1] + s[2] + s[3] + s[4] + s[5] + s[6] + s[7];
        unsigned long long anyb = __ballot(ss != 0.f);
        bool anyc = (anyb != 0ull);
#pragma unroll
        for (int r = 0; r < 8; ++r) mask[r] = anyc ? __ballot(sp[r] != 0.f) : 0ull;

        if (lane < NOUT) {
          float io = 0.f;
          if (anyc) {
#pragma unroll
            for (int r2 = 0; r2 < 8; ++r2) {
              unsigned long long mm = mask[r2];
              while (mm) {
                int l2 = __ffsll(mm) - 1; mm &= (mm - 1);
                int hp = l2 * 8 + r2;
                io += wout[(size_t)lane * NHID + hp];
              }
            }
          }
          vout = bo * vout + (1.0f - bo) * io;
          float so = (vout - 1.0f > 0.0f) ? 1.0f : 0.0f;
          vout -= so;
          osum += vout;
        }
        anyprev = anyc;

        int nt = (tl + 8 < Tc) ? (tl + 8) : (Tc - 1);
        pf[j] = *(const uint2*)(iff + ((size_t)nt * B_ + b) * NHID + hbase);
      }
    }
  }

  if (last) {
    if (lane < NOUT) dout[b * NOUT + lane] = osum / (float)T_;
  } else {
#pragma unroll
    for (int r = 0; r < 8; ++r) {
      int h = hbase + r;
      v1s[(size_t)b * NHID + h] = v1[r];
      a1s[(size_t)b * NHID + h] = a1[r];
      sps[(size_t)b * NHID + h] = sp[r];
    }
    if (lane < NOUT) { vos[b * NOUT + lane] = vout; oss[b * NOUT + lane] = osum; }
  }
}

extern "C" void kernel_launch(void* const* d_in, const int* in_sizes, int n_in,
                              void* d_out, int out_size, void* d_ws, size_t ws_size,
                              hipStream_t stream) {
  const float* x      = (const float*)d_in[0];
  const float* w1     = (const float*)d_in[1];
  const float* wrec   = (const float*)d_in[2];
  const float* wout   = (const float*)d_in[3];
  const float* alpha  = (const float*)d_in[4];
  const float* rho    = (const float*)d_in[5];
  const float* beta_a = (const float*)d_in[6];
  const float* bout   = (const float*)d_in[7];
  float* out = (float*)d_out;

  char* ws = (char*)d_ws;
  const size_t w1frag_bytes = (size_t)NKT * 32 * 64 * 8 * 2;                 // 704 KB
  const size_t state_off = w1frag_bytes;
  const size_t state_bytes = (size_t)(3 * B_ * NHID + 2 * B_ * NOUT) * 4;    // ~1.6 MB
  const size_t iff_off = state_off + state_bytes;

  ushort* w1frag = (ushort*)(ws);
  float*  statep = (float*)(ws + state_off);
  unsigned char* iff = (unsigned char*)(ws + iff_off);

  const size_t per_step = (size_t)B_ * NHID;  // 128 KB per timestep (fp8)
  long long avail = (long long)ws_size - (long long)iff_off;
  int Tc = (int)(avail / (long long)per_step);
  if (Tc > T_) Tc = T_;
  if (Tc < 1) Tc = 1;

  prep_kernel<<<dim3((NKT * 32 * 64 * 8 + 255) / 256), dim3(256), 0, stream>>>(
      w1, w1frag);

  for (int t0 = 0; t0 < T_; t0 += Tc) {
    int tc = (T_ - t0 < Tc) ? (T_ - t0) : Tc;
    gemm_mfma<<<dim3(2, tc * 4), dim3(256), 0, stream>>>(x, w1frag, iff, t0);
    snn_recur<<<dim3(B_), dim3(64), 0, stream>>>(
        iff, wrec, wout, alpha, rho, beta_a, bout, statep, out,
        tc, (t0 == 0) ? 1 : 0, (t0 + tc >= T_) ? 1 : 0);
  }
}

// Round 5
// 115.890 us; speedup vs baseline: 1.5699x; 1.5699x over previous
//
#include <hip/hip_runtime.h>
#include <hip/hip_bf16.h>
#include <hip/hip_fp8.h>

// SNN forward, round 5.
//   prep:      w1 -> w1frag bf16 fragment layout [kt][colblk][lane][8]
//   gemm_mfma: BM=64 x BN=512 (full N), 256 thr / 4 waves, wave tile 64x128.
//              B: global_load_lds(16B) -> LDS dbuf (32KB/tile), block-shared,
//              issued one full iteration ahead (counted pipeline, single
//              end-of-iter vmcnt+barrier). A: reg-staged f32->bf16 into
//              stride-80 LDS. 32 MFMA/wave/iter. Epilogue scales by (1-alpha),
//              stores fp8 e4m3. 2 blocks/CU (74KB LDS, ~200 VGPR).
//   snn_recur: fast path (no spike ever): v1 = a*v1 + ivs, max-check, 1 ballot.
//              Full LIF path retained as fallback via per-row flag.

#define B_    256
#define T_    250
#define NIN   700
#define KPAD  704
#define NKT   22          // KPAD/32
#define NHID  512
#define NOUT  20

typedef __attribute__((ext_vector_type(8))) short short8;
typedef __attribute__((ext_vector_type(4))) float f32x4;

static __device__ __forceinline__ ushort f2bf(float f) {
  union { float f; unsigned u; } v; v.f = f;
  unsigned r = (v.u + 0x7FFF + ((v.u >> 16) & 1)) >> 16;  // RNE
  return (ushort)r;
}
static __device__ __forceinline__ unsigned cvtpk_bf16(float a, float b) {
  unsigned r;
  asm("v_cvt_pk_bf16_f32 %0, %1, %2" : "=v"(r) : "v"(a), "v"(b));
  return r;
}
static __device__ __forceinline__ void gload_lds16(const void* g, void* l) {
  __builtin_amdgcn_global_load_lds(
      (const __attribute__((address_space(1))) unsigned*)g,
      (__attribute__((address_space(3))) unsigned*)l, 16, 0, 0);
}

// ---------------- prep: w1 -> bf16 fragment layout ----------------
// flat = ((kt*32 + colblk)*64 + (koct*16 + colm))*8 + e
__global__ __launch_bounds__(256) void prep_kernel(
    const float* __restrict__ w1, ushort* __restrict__ w1frag) {
  int i = blockIdx.x * 256 + threadIdx.x;
  if (i >= NKT * 32 * 64 * 8) return;
  int e      = i & 7;
  int colm   = (i >> 3) & 15;
  int koct   = (i >> 7) & 3;
  int colblk = (i >> 9) & 31;
  int kt     = i >> 14;
  int k   = kt * 32 + koct * 8 + e;
  int col = colblk * 16 + colm;
  w1frag[i] = (k < NIN) ? f2bf(w1[(size_t)col * NIN + k]) : (ushort)0;
}

// ---------------- MFMA GEMM ----------------
// grid = (tc*4); block = 256 (4 waves), wave tile 64x128, BN=512 full
__global__ __launch_bounds__(256, 2) void gemm_mfma(
    const float* __restrict__ x, const ushort* __restrict__ w1frag,
    const float* __restrict__ alpha,
    unsigned char* __restrict__ iff, int t0) {
  __shared__ __align__(16) ushort Bbuf[2][16384];   // 2 x 32 KB
  __shared__ __align__(16) char   Abuf[2][64 * 80]; // 2 x 5 KB

  int tid  = threadIdx.x;
  int lane = tid & 63;
  int wave = tid >> 6;           // n-quarter: cols wave*128..+127
  int gy   = blockIdx.x;         // 64-row m-chunk
  int m0 = gy * 64;
  int t  = t0 + (gy >> 2);
  int b0 = (gy & 3) * 64;

  // A staging: thread -> (row, k-quad)
  int srow = tid >> 2;           // 0..63
  int skq  = tid & 3;            // 8 f32 at k = kt*32 + skq*8
  const float* ap = x + ((size_t)(b0 + srow) * T_ + t) * NIN;
  int swb = srow * 80 + skq * 16;

  int lm = lane & 15, lk = lane >> 4;

  f32x4 acc[4][8];
#pragma unroll
  for (int i = 0; i < 4; ++i)
#pragma unroll
    for (int j = 0; j < 8; ++j) acc[i][j] = (f32x4){0.f, 0.f, 0.f, 0.f};

#define LOADA(d0, d1, KT) do {                                               \
    int k0_ = (KT) * 32 + skq * 8;                                           \
    if (k0_ + 8 <= NIN) {                                                    \
      d0 = *(const float4*)(ap + k0_); d1 = *(const float4*)(ap + k0_ + 4);  \
    } else if (k0_ + 4 <= NIN) {                                             \
      d0 = *(const float4*)(ap + k0_); d1 = (float4){0.f,0.f,0.f,0.f};       \
    } else { d0 = (float4){0.f,0.f,0.f,0.f}; d1 = (float4){0.f,0.f,0.f,0.f}; } \
  } while (0)

#define WRITEA(BUF, s0, s1) do {                                             \
    uint4 pk_;                                                               \
    pk_.x = cvtpk_bf16(s0.x, s0.y); pk_.y = cvtpk_bf16(s0.z, s0.w);          \
    pk_.z = cvtpk_bf16(s1.x, s1.y); pk_.w = cvtpk_bf16(s1.z, s1.w);          \
    *(uint4*)(&Abuf[BUF][swb]) = pk_;                                        \
  } while (0)

  // B stage: 32 KB slab, 32 x 1KB wave-chunks; dest = uniform base (+HW lane*16)
#define STAGE_B(BUF, KT) do {                                                \
    const char* gs_ = (const char*)w1frag + (size_t)(KT) * 32768;            \
    char* ls_ = (char*)&Bbuf[BUF][0];                                        \
    _Pragma("unroll")                                                        \
    for (int i_ = 0; i_ < 8; ++i_) {                                         \
      int off_ = (i_ * 4 + wave) * 1024;                                     \
      gload_lds16(gs_ + off_ + lane * 16, ls_ + off_);                       \
    }                                                                        \
  } while (0)

  float4 a0s, a1s;
  // prologue: A0 -> Abuf[0]; B0 staged async
  LOADA(a0s, a1s, 0);
  STAGE_B(0, 0);
  WRITEA(0, a0s, a1s);
  asm volatile("s_waitcnt vmcnt(0) lgkmcnt(0)" ::: "memory");
  __builtin_amdgcn_s_barrier();
  __builtin_amdgcn_sched_barrier(0);

#pragma unroll 2
  for (int kt = 0; kt < NKT; ++kt) {
    const int cur = kt & 1;
    const int nxt = cur ^ 1;
    // issue next tile's loads FIRST (A regs, then B async-to-LDS)
    if (kt + 1 < NKT) {
      LOADA(a0s, a1s, kt + 1);
      STAGE_B(nxt, kt + 1);
    }
    // fragments from current buffers
    short8 af[4], bf[8];
#pragma unroll
    for (int i = 0; i < 4; ++i)
      af[i] = *(const short8*)(&Abuf[cur][(i * 16 + lm) * 80 + lk * 16]);
#pragma unroll
    for (int j = 0; j < 8; ++j)
      bf[j] = *(const short8*)(&Bbuf[cur][((wave * 8 + j) * 64 + lane) * 8]);
    // MFMA cluster
    __builtin_amdgcn_s_setprio(1);
#pragma unroll
    for (int i = 0; i < 4; ++i)
#pragma unroll
      for (int j = 0; j < 8; ++j)
        acc[i][j] = __builtin_amdgcn_mfma_f32_16x16x32_bf16(
            af[i], bf[j], acc[i][j], 0, 0, 0);
    __builtin_amdgcn_s_setprio(0);
    // convert+write next A tile (waits only the 2 A loads; B stays in flight)
    if (kt + 1 < NKT) {
      WRITEA(nxt, a0s, a1s);
      asm volatile("s_waitcnt vmcnt(0) lgkmcnt(0)" ::: "memory");
      __builtin_amdgcn_s_barrier();
      __builtin_amdgcn_sched_barrier(0);
    }
  }
#undef LOADA
#undef WRITEA
#undef STAGE_B

  // epilogue: scale by (1-alpha[col]), store fp8 e4m3
  float scl[8];
#pragma unroll
  for (int j = 0; j < 8; ++j) scl[j] = 1.0f - alpha[wave * 128 + j * 16 + lm];
#pragma unroll
  for (int i = 0; i < 4; ++i) {
#pragma unroll
    for (int r = 0; r < 4; ++r) {
      int row = m0 + i * 16 + lk * 4 + r;
      unsigned char* op = iff + (size_t)row * NHID + wave * 128 + lm;
#pragma unroll
      for (int j = 0; j < 8; ++j) {
        __hip_fp8_e4m3 q(acc[i][j][r] * scl[j]);
        op[j * 16] = q.__x;
      }
    }
  }
}

// ---------------- fused recurrence ----------------
// 256 blocks x 64 threads; block b = batch row. Lane owns 8 h.
// iff is PRE-SCALED by (1-alpha). Fast path while no spike has ever fired.
__global__ __launch_bounds__(64) void snn_recur(
    const unsigned char* __restrict__ iff, const float* __restrict__ wrec,
    const float* __restrict__ wout,
    const float* __restrict__ alpha, const float* __restrict__ rho,
    const float* __restrict__ beta_a, const float* __restrict__ beta_out,
    float* __restrict__ state, int* __restrict__ flags,
    float* __restrict__ dout, int Tc, int first, int last) {
  int lane = threadIdx.x;
  int b = blockIdx.x;
  int hbase = lane * 8;

  float* v1s = state;
  float* a1s = state + B_ * NHID;
  float* sps = state + 2 * B_ * NHID;
  float* vos = state + 3 * B_ * NHID;
  float* oss = vos + B_ * NOUT;

  float v1[8], a1[8], sp[8], al[8], rh[8], ba[8];
#pragma unroll
  for (int r = 0; r < 8; ++r) {
    int h = hbase + r;
    al[r] = alpha[h]; rh[r] = rho[h]; ba[r] = beta_a[h];
    if (first) { v1[r] = 0.f; a1[r] = 0.f; sp[r] = 0.f; }
    else {
      v1[r] = v1s[(size_t)b * NHID + h];
      a1[r] = a1s[(size_t)b * NHID + h];
      sp[r] = sps[(size_t)b * NHID + h];
    }
  }
  float vout = 0.f, osum = 0.f, bo = 0.f;
  if (lane < NOUT) {
    bo = beta_out[lane];
    if (!first) { vout = vos[b * NOUT + lane]; osum = oss[b * NOUT + lane]; }
  }

  int mode = first ? 0 : flags[b];
  int tle = 0;

  if (mode == 0) {
    // ---------------- fast path: no spike has ever fired ----------------
    uint2 pf[8];
#pragma unroll
    for (int j = 0; j < 8; ++j) {
      int tl = (j < Tc) ? j : (Tc - 1);
      pf[j] = *(const uint2*)(iff + ((size_t)tl * B_ + b) * NHID + hbase);
    }
    bool esc = false;
    for (int tb = 0; tb < Tc && !esc; tb += 8) {
#pragma unroll
      for (int j = 0; j < 8; ++j) {
        int tl = tb + j;
        if (!esc && tl < Tc) {
          float tv[8];
#pragma unroll
          for (int r = 0; r < 8; ++r) {
            unsigned w = (r < 4) ? pf[j].x : pf[j].y;
            __hip_fp8_e4m3 q; q.__x = (unsigned char)((w >> ((r & 3) * 8)) & 255u);
            tv[r] = al[r] * v1[r] + (float)q;   // ivs pre-scaled by (1-alpha)
          }
          float m01 = fmaxf(tv[0], tv[1]), m23 = fmaxf(tv[2], tv[3]);
          float m45 = fmaxf(tv[4], tv[5]), m67 = fmaxf(tv[6], tv[7]);
          float mx = fmaxf(fmaxf(m01, m23), fmaxf(m45, m67));
          if (__ballot(mx > 1.0f)) {
            esc = true; tle = tl;   // redo step tl in full mode (v1 uncommitted)
          } else {
#pragma unroll
            for (int r = 0; r < 8; ++r) v1[r] = tv[r];
            int nt = (tl + 8 < Tc) ? (tl + 8) : (Tc - 1);
            pf[j] = *(const uint2*)(iff + ((size_t)nt * B_ + b) * NHID + hbase);
          }
        }
      }
    }
    if (!esc) tle = Tc;
    mode = esc ? 1 : 0;
    // vout/osum/a1/sp remain as loaded (all zero in fast mode)
  }

  // ---------------- full path (fallback; also post-spike chunks) ----------------
  unsigned long long mask[8];
#pragma unroll
  for (int r = 0; r < 8; ++r) mask[r] = __ballot(sp[r] != 0.f);

  for (int tl = tle; tl < Tc; ++tl) {
    uint2 w2 = *(const uint2*)(iff + ((size_t)tl * B_ + b) * NHID + hbase);
    float iv[8];
#pragma unroll
    for (int r = 0; r < 8; ++r) {
      unsigned w = (r < 4) ? w2.x : w2.y;
      __hip_fp8_e4m3 q; q.__x = (unsigned char)((w >> ((r & 3) * 8)) & 255u);
      iv[r] = (float)q;   // = (1-alpha)*i_ff
    }
    // recurrent input from previous spikes: iv += (1-alpha)*sum(wrec rows)
    unsigned long long anyp = mask[0] | mask[1] | mask[2] | mask[3] |
                              mask[4] | mask[5] | mask[6] | mask[7];
    if (anyp) {
      float rec[8] = {0.f,0.f,0.f,0.f,0.f,0.f,0.f,0.f};
#pragma unroll
      for (int r2 = 0; r2 < 8; ++r2) {
        unsigned long long mm = mask[r2];
        while (mm) {
          int l2 = __ffsll(mm) - 1; mm &= (mm - 1);
          int hp = l2 * 8 + r2;
#pragma unroll
          for (int r = 0; r < 8; ++r)
            rec[r] += wrec[(size_t)(hbase + r) * NHID + hp];
        }
      }
#pragma unroll
      for (int r = 0; r < 8; ++r) iv[r] += (1.0f - al[r]) * rec[r];
    }

    float s[8];
#pragma unroll
    for (int r = 0; r < 8; ++r) {
      a1[r] = rh[r] * a1[r] + ba[r] * sp[r];
      v1[r] = al[r] * v1[r] + iv[r] - a1[r];
      s[r] = (v1[r] - 1.0f > 0.0f) ? 1.0f : 0.0f;
      v1[r] -= s[r];
      sp[r] = s[r];
      mask[r] = __ballot(s[r] != 0.f);
    }

    unsigned long long anyc = mask[0] | mask[1] | mask[2] | mask[3] |
                              mask[4] | mask[5] | mask[6] | mask[7];
    if (lane < NOUT) {
      float io = 0.f;
      if (anyc) {
#pragma unroll
        for (int r2 = 0; r2 < 8; ++r2) {
          unsigned long long mm = mask[r2];
          while (mm) {
            int l2 = __ffsll(mm) - 1; mm &= (mm - 1);
            int hp = l2 * 8 + r2;
            io += wout[(size_t)lane * NHID + hp];
          }
        }
      }
      vout = bo * vout + (1.0f - bo) * io;
      float so = (vout - 1.0f > 0.0f) ? 1.0f : 0.0f;
      vout -= so;
      osum += vout;
    }
  }

  if (last) {
    if (lane < NOUT) dout[b * NOUT + lane] = osum / (float)T_;
  } else {
#pragma unroll
    for (int r = 0; r < 8; ++r) {
      int h = hbase + r;
      v1s[(size_t)b * NHID + h] = v1[r];
      a1s[(size_t)b * NHID + h] = a1[r];
      sps[(size_t)b * NHID + h] = sp[r];
    }
    if (lane < NOUT) { vos[b * NOUT + lane] = vout; oss[b * NOUT + lane] = osum; }
    if (lane == 0) flags[b] = mode;
  }
}

extern "C" void kernel_launch(void* const* d_in, const int* in_sizes, int n_in,
                              void* d_out, int out_size, void* d_ws, size_t ws_size,
                              hipStream_t stream) {
  const float* x      = (const float*)d_in[0];
  const float* w1     = (const float*)d_in[1];
  const float* wrec   = (const float*)d_in[2];
  const float* wout   = (const float*)d_in[3];
  const float* alpha  = (const float*)d_in[4];
  const float* rho    = (const float*)d_in[5];
  const float* beta_a = (const float*)d_in[6];
  const float* bout   = (const float*)d_in[7];
  float* out = (float*)d_out;

  char* ws = (char*)d_ws;
  const size_t w1frag_bytes = (size_t)NKT * 32 * 64 * 8 * 2;                 // 704 KB
  const size_t state_off = w1frag_bytes;
  const size_t state_bytes = (size_t)(3 * B_ * NHID + 2 * B_ * NOUT) * 4;
  const size_t flags_off = state_off + state_bytes;
  const size_t iff_off   = flags_off + B_ * 4;

  ushort* w1frag = (ushort*)(ws);
  float*  statep = (float*)(ws + state_off);
  int*    flagsp = (int*)(ws + flags_off);
  unsigned char* iff = (unsigned char*)(ws + iff_off);

  const size_t per_step = (size_t)B_ * NHID;  // 128 KB per timestep (fp8)
  long long avail = (long long)ws_size - (long long)iff_off;
  int Tc = (int)(avail / (long long)per_step);
  if (Tc > T_) Tc = T_;
  if (Tc < 1) Tc = 1;

  prep_kernel<<<dim3((NKT * 32 * 64 * 8 + 255) / 256), dim3(256), 0, stream>>>(
      w1, w1frag);

  for (int t0 = 0; t0 < T_; t0 += Tc) {
    int tc = (T_ - t0 < Tc) ? (T_ - t0) : Tc;
    gemm_mfma<<<dim3(tc * 4), dim3(256), 0, stream>>>(x, w1frag, alpha, iff, t0);
    snn_recur<<<dim3(B_), dim3(64), 0, stream>>>(
        iff, wrec, wout, alpha, rho, beta_a, bout, statep, flagsp, out,
        tc, (t0 == 0) ? 1 : 0, (t0 + tc >= T_) ? 1 : 0);
  }
}